// Round 1
// baseline (391.220 us; speedup 1.0000x reference)
//
#include <hip/hip_runtime.h>

// CA update: x(16,256,256,16) fp32; perceive(ident,sobelx,sobely)->48ch;
// MLP 48->128 relu ->16; x += dx*(rand<=0.5); out = x_new * (pre&post alive 3x3 max alpha>0.1)

#define NB 16
#define NH 256
#define NW 256
#define NC 16
#define NHID 128
#define NPIX (NB*NH*NW)

__global__ __launch_bounds__(256) void ca_update(
    const float* __restrict__ x, const float* __restrict__ W1,
    const float* __restrict__ b1, const float* __restrict__ W2,
    const float* __restrict__ b2, const float* __restrict__ rand_u,
    float* __restrict__ out, float* __restrict__ ws_alpha, float* __restrict__ ws_pre)
{
    // 18x18 halo tile, per-pixel stride 17 floats (odd -> no LDS bank pathology)
    __shared__ float tile[18 * 18 * 17];

    const int tid = threadIdx.x;
    const int w0 = blockIdx.x * 16;
    const int h0 = blockIdx.y * 16;
    const int bb = blockIdx.z;

    // ---- load x tile + halo (zero padded; zero-pad is equivalent to -inf pad
    // for the >0.1 alive test since 0 < 0.1) ----
    for (int i = tid; i < 18 * 18; i += 256) {
        const int ly = i / 18, lx = i - ly * 18;
        const int gh = h0 + ly - 1, gw = w0 + lx - 1;
        float4 v0, v1, v2, v3;
        if (gh >= 0 && gh < NH && gw >= 0 && gw < NW) {
            const float4* p = (const float4*)(x + (((size_t)bb * NH + gh) * NW + gw) * NC);
            v0 = p[0]; v1 = p[1]; v2 = p[2]; v3 = p[3];
        } else {
            v0 = v1 = v2 = v3 = make_float4(0.f, 0.f, 0.f, 0.f);
        }
        float* t = &tile[i * 17];
        t[0]=v0.x; t[1]=v0.y; t[2]=v0.z; t[3]=v0.w;
        t[4]=v1.x; t[5]=v1.y; t[6]=v1.z; t[7]=v1.w;
        t[8]=v2.x; t[9]=v2.y; t[10]=v2.z; t[11]=v2.w;
        t[12]=v3.x; t[13]=v3.y; t[14]=v3.z; t[15]=v3.w;
    }
    __syncthreads();

    const int tx = tid & 15, ty = tid >> 4;
    const int lcc = ((ty + 1) * 18 + (tx + 1)) * 17;   // center
    const int lmm = (ty * 18 + tx) * 17;               // (h-1,w-1)
    const int lm0 = (ty * 18 + tx + 1) * 17;           // (h-1,w)
    const int lmp = (ty * 18 + tx + 2) * 17;           // (h-1,w+1)
    const int l0m = ((ty + 1) * 18 + tx) * 17;         // (h,w-1)
    const int l0p = ((ty + 1) * 18 + tx + 2) * 17;     // (h,w+1)
    const int lpm = ((ty + 2) * 18 + tx) * 17;         // (h+1,w-1)
    const int lp0 = ((ty + 2) * 18 + tx + 1) * 17;     // (h+1,w)
    const int lpp = ((ty + 2) * 18 + tx + 2) * 17;     // (h+1,w+1)

    // ---- perceive: y[3c+0]=ident, y[3c+1]=sobel-x, y[3c+2]=sobel-y ----
    float y[48];
    #pragma unroll
    for (int c = 0; c < NC; ++c) {
        const float xmm = tile[lmm + c], xm0 = tile[lm0 + c], xmp = tile[lmp + c];
        const float x0m = tile[l0m + c], xcc = tile[lcc + c], x0p = tile[l0p + c];
        const float xpm = tile[lpm + c], xp0 = tile[lp0 + c], xpp = tile[lpp + c];
        y[3*c + 0] = xcc;
        y[3*c + 1] = ((xmp - xmm) + 2.f * (x0p - x0m) + (xpp - xpm)) * 0.125f;
        y[3*c + 2] = ((xpm - xmm) + 2.f * (xp0 - xm0) + (xpp - xmp)) * 0.125f;
    }

    // ---- pre-life mask: 3x3 max of original alpha (channel 3) ----
    float am = tile[lmm + 3];
    am = fmaxf(am, tile[lm0 + 3]); am = fmaxf(am, tile[lmp + 3]);
    am = fmaxf(am, tile[l0m + 3]); am = fmaxf(am, tile[lcc + 3]);
    am = fmaxf(am, tile[l0p + 3]);
    am = fmaxf(am, tile[lpm + 3]); am = fmaxf(am, tile[lp0 + 3]);
    am = fmaxf(am, tile[lpp + 3]);
    const float pre = (am > 0.1f) ? 1.f : 0.f;

    // ---- MLP: h = relu(y@W1+b1); dx = h@W2+b2 ----
    float dxacc[NC];
    #pragma unroll
    for (int c = 0; c < NC; ++c) dxacc[c] = b2[c];

    for (int d0 = 0; d0 < NHID; d0 += 4) {
        float a0 = b1[d0 + 0], a1 = b1[d0 + 1], a2 = b1[d0 + 2], a3 = b1[d0 + 3];
        #pragma unroll
        for (int c = 0; c < 48; ++c) {
            const float* wp = &W1[c * NHID + d0];   // wave-uniform -> s_load
            const float yc = y[c];
            a0 = fmaf(yc, wp[0], a0);
            a1 = fmaf(yc, wp[1], a1);
            a2 = fmaf(yc, wp[2], a2);
            a3 = fmaf(yc, wp[3], a3);
        }
        a0 = fmaxf(a0, 0.f); a1 = fmaxf(a1, 0.f);
        a2 = fmaxf(a2, 0.f); a3 = fmaxf(a3, 0.f);
        const float* w2p = &W2[d0 * NC];            // wave-uniform -> s_load
        #pragma unroll
        for (int c = 0; c < NC; ++c) {
            float t = fmaf(a0, w2p[c], dxacc[c]);
            t = fmaf(a1, w2p[NC + c], t);
            t = fmaf(a2, w2p[2 * NC + c], t);
            dxacc[c] = fmaf(a3, w2p[3 * NC + c], t);
        }
    }

    // ---- stochastic update ----
    const size_t pix = ((size_t)bb * NH + (h0 + ty)) * NW + (w0 + tx);
    const float um = (rand_u[pix] <= 0.5f) ? 1.f : 0.f;
    float nx[NC];
    #pragma unroll
    for (int c = 0; c < NC; ++c) nx[c] = fmaf(dxacc[c], um, tile[lcc + c]);

    float4* po = (float4*)(out + pix * NC);
    po[0] = make_float4(nx[0], nx[1], nx[2], nx[3]);
    po[1] = make_float4(nx[4], nx[5], nx[6], nx[7]);
    po[2] = make_float4(nx[8], nx[9], nx[10], nx[11]);
    po[3] = make_float4(nx[12], nx[13], nx[14], nx[15]);
    ws_alpha[pix] = nx[3];
    ws_pre[pix] = pre;
}

__global__ __launch_bounds__(256) void ca_mask(
    const float* __restrict__ ws_alpha, const float* __restrict__ ws_pre,
    float* __restrict__ out)
{
    const size_t pix = (size_t)blockIdx.x * 256 + threadIdx.x;
    const int w = (int)(pix & 255);
    const int h = (int)((pix >> 8) & 255);
    const size_t base = pix - w - ((size_t)h << 8);  // b*65536

    float m = -1e30f;
    #pragma unroll
    for (int dy = -1; dy <= 1; ++dy) {
        const int hh = h + dy;
        if (hh < 0 || hh >= NH) continue;
        const size_t row = base + (size_t)hh * NW;
        #pragma unroll
        for (int dw = -1; dw <= 1; ++dw) {
            const int ww = w + dw;
            if (ww < 0 || ww >= NW) continue;
            m = fmaxf(m, ws_alpha[row + ww]);
        }
    }
    const bool life = (ws_pre[pix] != 0.f) && (m > 0.1f);
    const float s = life ? 1.f : 0.f;

    float4* po = (float4*)(out + pix * NC);
    #pragma unroll
    for (int i = 0; i < 4; ++i) {
        float4 v = po[i];
        v.x *= s; v.y *= s; v.z *= s; v.w *= s;
        po[i] = v;
    }
}

extern "C" void kernel_launch(void* const* d_in, const int* in_sizes, int n_in,
                              void* d_out, int out_size, void* d_ws, size_t ws_size,
                              hipStream_t stream) {
    (void)in_sizes; (void)n_in; (void)out_size; (void)ws_size;
    const float* x      = (const float*)d_in[0];
    const float* W1     = (const float*)d_in[1];
    const float* b1     = (const float*)d_in[2];
    const float* W2     = (const float*)d_in[3];
    const float* b2     = (const float*)d_in[4];
    const float* rand_u = (const float*)d_in[5];
    float* out = (float*)d_out;
    float* ws_alpha = (float*)d_ws;           // NPIX floats
    float* ws_pre   = ws_alpha + NPIX;        // NPIX floats (8 MiB total)

    dim3 gridA(NW / 16, NH / 16, NB);
    ca_update<<<gridA, 256, 0, stream>>>(x, W1, b1, W2, b2, rand_u, out, ws_alpha, ws_pre);
    ca_mask<<<NPIX / 256, 256, 0, stream>>>(ws_alpha, ws_pre, out);
}

// Round 2
// 340.032 us; speedup vs baseline: 1.1505x; 1.1505x over previous
//
#include <hip/hip_runtime.h>

// Neural-CA update step, MI355X/gfx950.
// Structure: ca_prep packs W1(+b1 as K=48 row)/W2 into MFMA bf16 fragments in d_ws.
// ca_update: per 16x16 tile, perceive stencil (fp32) -> bf16 y-frags in LDS ->
//   GEMM1 (hid = W1^T @ y^T, 16 MFMA/row-tile) -> relu/bf16 h via LDS ->
//   GEMM2 (dx^T = W2^T @ h^T, 4 MFMA) -> coalesced float4 stores.
// ca_mask: 3x3 max of new alpha with +-0.015 margin; boundary pixels get exact
//   fp32 MLP recompute (rare, ~5e-4 of pixels) so mask decisions match the
//   fp32 reference despite bf16 GEMMs.

#define NC 16
#define NHID 128
#define NPIX (16 * 256 * 256)
#define MG 0.015f

typedef __attribute__((ext_vector_type(8))) short s8b;   // 8 x bf16 (4 VGPRs)
typedef __attribute__((ext_vector_type(4))) float f4;

__device__ __forceinline__ unsigned short f2bf(float f) {
    union { float f; unsigned int u; } v; v.f = f;
    unsigned int r = (v.u + 0x7FFFu + ((v.u >> 16) & 1u)) >> 16;  // RNE
    return (unsigned short)r;
}
__device__ __forceinline__ unsigned int pack2(float a, float b) {
    return (unsigned int)f2bf(a) | ((unsigned int)f2bf(b) << 16);
}

// ---------------- prep: pack weights into MFMA fragment order ----------------
// w1p[fid*64+lane], fid=(k0*8+mt): A-frag of W1^T: elem j -> W1[k0*32+q*8+j][mt*16+i]
//   (k==48 row = b1, folded bias; k>48 = 0). w2p[k2*64+lane]: W2[(k2*32+q*8+j)*16+i].
__global__ __launch_bounds__(256) void ca_prep(
    const float* __restrict__ W1, const float* __restrict__ b1,
    const float* __restrict__ W2, uint4* __restrict__ w1p, uint4* __restrict__ w2p)
{
    const int tid = threadIdx.x;
    if (blockIdx.x == 0) {
        for (int idx = tid; idx < 1024; idx += 256) {
            const int fid = idx >> 6, lane = idx & 63;
            const int k0 = fid >> 3, mt = fid & 7;
            const int q = lane >> 4, i = lane & 15;
            unsigned int u[4];
            #pragma unroll
            for (int jp = 0; jp < 4; ++jp) {
                int k = k0 * 32 + q * 8 + jp * 2;
                float v0 = (k < 48) ? W1[k * 128 + mt * 16 + i] : ((k == 48) ? b1[mt * 16 + i] : 0.f);
                k++;
                float v1 = (k < 48) ? W1[k * 128 + mt * 16 + i] : ((k == 48) ? b1[mt * 16 + i] : 0.f);
                u[jp] = pack2(v0, v1);
            }
            w1p[idx] = make_uint4(u[0], u[1], u[2], u[3]);
        }
    } else {
        for (int idx = tid; idx < 256; idx += 256) {
            const int k2 = idx >> 6, lane = idx & 63;
            const int q = lane >> 4, i = lane & 15;
            unsigned int u[4];
            #pragma unroll
            for (int jp = 0; jp < 4; ++jp) {
                const int k = k2 * 32 + q * 8 + jp * 2;
                u[jp] = pack2(W2[k * 16 + i], W2[(k + 1) * 16 + i]);
            }
            w2p[idx] = make_uint4(u[0], u[1], u[2], u[3]);
        }
    }
}

// ---------------- main update kernel ----------------
__global__ __launch_bounds__(256, 2) void ca_update(
    const float* __restrict__ x, const float* __restrict__ b2,
    const float* __restrict__ rand_u, const uint4* __restrict__ w1p,
    const uint4* __restrict__ w2p, float* __restrict__ out,
    float* __restrict__ ws_alpha, unsigned char* __restrict__ ws_pre)
{
    __shared__ __align__(16) float xt[18 * 18 * 20];          // 18x18 halo, stride 20 (16B-aligned pixels)
    __shared__ __align__(16) unsigned short yfs[4 * 2 * 528]; // per-wave y B-frags (2 K-steps, 16-short pad)
    __shared__ __align__(16) unsigned short hbs[4 * 16 * 136];// per-wave h rows [pixel][hid], stride 136
    __shared__ float lsr[256];

    const int tid  = threadIdx.x;
    const int lane = tid & 63;
    const int li   = lane & 15;   // n-index (pixel col in frags)
    const int lq   = lane >> 4;   // quad
    const int wv   = tid >> 6;
    const int tx   = tid & 15, ty = tid >> 4;
    const int w0 = blockIdx.x * 16, h0 = blockIdx.y * 16, bb = blockIdx.z;

    // weight fragments from prepacked workspace (lane-major, coalesced, L2-hot)
    s8b w1f[2][8], w2f[4];
    const s8b* w1s = (const s8b*)w1p;
    const s8b* w2s = (const s8b*)w2p;
    #pragma unroll
    for (int k0 = 0; k0 < 2; ++k0)
        #pragma unroll
        for (int mt = 0; mt < 8; ++mt)
            w1f[k0][mt] = w1s[(k0 * 8 + mt) * 64 + lane];
    #pragma unroll
    for (int k2 = 0; k2 < 4; ++k2) w2f[k2] = w2s[k2 * 64 + lane];
    float b2v[4];
    #pragma unroll
    for (int r = 0; r < 4; ++r) b2v[r] = b2[lq * 4 + r];

    // ---- x tile + halo (zero pad; 0 < 0.1 so equivalent for alive test) ----
    for (int i = tid; i < 324; i += 256) {
        const int ly = i / 18, lx = i - ly * 18;
        const int gh = h0 + ly - 1, gw = w0 + lx - 1;
        float4 v0, v1, v2, v3;
        if (gh >= 0 && gh < 256 && gw >= 0 && gw < 256) {
            const float4* p = (const float4*)(x + (((size_t)bb * 256 + gh) * 256 + gw) * NC);
            v0 = p[0]; v1 = p[1]; v2 = p[2]; v3 = p[3];
        } else {
            v0 = v1 = v2 = v3 = make_float4(0.f, 0.f, 0.f, 0.f);
        }
        float4* t = (float4*)(xt + i * 20);
        t[0] = v0; t[1] = v1; t[2] = v2; t[3] = v3;
    }
    const size_t gpix = ((size_t)bb * 256 + h0 + ty) * 256 + (w0 + tx);
    lsr[tid] = rand_u[gpix];
    __syncthreads();

    const int o_mm = ((ty + 0) * 18 + tx + 0) * 20, o_m0 = ((ty + 0) * 18 + tx + 1) * 20, o_mp = ((ty + 0) * 18 + tx + 2) * 20;
    const int o_0m = ((ty + 1) * 18 + tx + 0) * 20, o_cc = ((ty + 1) * 18 + tx + 1) * 20, o_0p = ((ty + 1) * 18 + tx + 2) * 20;
    const int o_pm = ((ty + 2) * 18 + tx + 0) * 20, o_p0 = ((ty + 2) * 18 + tx + 1) * 20, o_pp = ((ty + 2) * 18 + tx + 2) * 20;

    // pre-life mask from ORIGINAL alpha (exact fp32 -> no flip risk)
    float am = xt[o_mm + 3];
    am = fmaxf(am, xt[o_m0 + 3]); am = fmaxf(am, xt[o_mp + 3]);
    am = fmaxf(am, xt[o_0m + 3]); am = fmaxf(am, xt[o_cc + 3]); am = fmaxf(am, xt[o_0p + 3]);
    am = fmaxf(am, xt[o_pm + 3]); am = fmaxf(am, xt[o_p0 + 3]); am = fmaxf(am, xt[o_pp + 3]);
    ws_pre[gpix] = (am > 0.1f) ? (unsigned char)1 : (unsigned char)0;

    // ---- perceive: y[48] packed as bf16 pairs (yu[24]) ----
    unsigned int yu[24];
    #pragma unroll
    for (int cq = 0; cq < 4; ++cq) {
        const int co = cq * 4;
        float4 vmm = *(const float4*)(xt + o_mm + co); const float* pmm = (const float*)&vmm;
        float4 vm0 = *(const float4*)(xt + o_m0 + co); const float* pm0 = (const float*)&vm0;
        float4 vmp = *(const float4*)(xt + o_mp + co); const float* pmp = (const float*)&vmp;
        float4 v0m = *(const float4*)(xt + o_0m + co); const float* p0m = (const float*)&v0m;
        float4 vcc = *(const float4*)(xt + o_cc + co); const float* pcc = (const float*)&vcc;
        float4 v0p = *(const float4*)(xt + o_0p + co); const float* p0p = (const float*)&v0p;
        float4 vpm = *(const float4*)(xt + o_pm + co); const float* ppm = (const float*)&vpm;
        float4 vp0 = *(const float4*)(xt + o_p0 + co); const float* pp0 = (const float*)&vp0;
        float4 vpp = *(const float4*)(xt + o_pp + co); const float* ppp = (const float*)&vpp;
        float yl[12];
        #pragma unroll
        for (int cc = 0; cc < 4; ++cc) {
            const float xmm = pmm[cc], xm0 = pm0[cc], xmp = pmp[cc];
            const float x0m = p0m[cc], xcc = pcc[cc], x0p = p0p[cc];
            const float xpm = ppm[cc], xp0 = pp0[cc], xpp = ppp[cc];
            yl[cc * 3 + 0] = xcc;
            yl[cc * 3 + 1] = ((xmp - xmm) + 2.f * (x0p - x0m) + (xpp - xpm)) * 0.125f;
            yl[cc * 3 + 2] = ((xpm - xmm) + 2.f * (xp0 - xm0) + (xpp - xmp)) * 0.125f;
        }
        #pragma unroll
        for (int m2 = 0; m2 < 6; ++m2) yu[cq * 6 + m2] = pack2(yl[2 * m2], yl[2 * m2 + 1]);
    }

    unsigned short* yfw = yfs + wv * (2 * 528);
    unsigned short* hbw = hbs + wv * (16 * 136);

    // ---- per row-of-16-pixels: GEMM1 -> h -> GEMM2 -> epilogue ----
    for (int s = 0; s < 4; ++s) {
        const int t = wv * 4 + s;
        if ((ty & 3) == s) {  // this quad's threads own row t: stage y B-frags
            #pragma unroll
            for (int q = 0; q < 4; ++q)
                *(uint4*)(yfw + (q * 16 + tx) * 8) = make_uint4(yu[q * 4], yu[q * 4 + 1], yu[q * 4 + 2], yu[q * 4 + 3]);
            *(uint4*)(yfw + 528 + (0 * 16 + tx) * 8) = make_uint4(yu[16], yu[17], yu[18], yu[19]);
            *(uint4*)(yfw + 528 + (1 * 16 + tx) * 8) = make_uint4(yu[20], yu[21], yu[22], yu[23]);
            *(uint4*)(yfw + 528 + (2 * 16 + tx) * 8) = make_uint4(0x3F80u, 0u, 0u, 0u);  // k=48 -> 1.0 (bias)
            *(uint4*)(yfw + 528 + (3 * 16 + tx) * 8) = make_uint4(0u, 0u, 0u, 0u);
        }
        __syncthreads();
        const s8b ya0 = *(const s8b*)(yfw + lane * 8);
        const s8b ya1 = *(const s8b*)(yfw + 528 + lane * 8);
        f4 acc1[8];
        #pragma unroll
        for (int mt = 0; mt < 8; ++mt) { f4 z = {0.f, 0.f, 0.f, 0.f}; acc1[mt] = z; }
        #pragma unroll
        for (int mt = 0; mt < 8; ++mt)
            acc1[mt] = __builtin_amdgcn_mfma_f32_16x16x32_bf16(w1f[0][mt], ya0, acc1[mt], 0, 0, 0);
        #pragma unroll
        for (int mt = 0; mt < 8; ++mt)
            acc1[mt] = __builtin_amdgcn_mfma_f32_16x16x32_bf16(w1f[1][mt], ya1, acc1[mt], 0, 0, 0);
        // D1[m=hid][n=pixel]: lane holds hid = mt*16+lq*4+r, pixel = li -> h rows [pixel][hid]
        #pragma unroll
        for (int mt = 0; mt < 8; ++mt) {
            const float hh0 = fmaxf(acc1[mt][0], 0.f), hh1 = fmaxf(acc1[mt][1], 0.f);
            const float hh2 = fmaxf(acc1[mt][2], 0.f), hh3 = fmaxf(acc1[mt][3], 0.f);
            *(uint2*)(hbw + li * 136 + mt * 16 + lq * 4) = make_uint2(pack2(hh0, hh1), pack2(hh2, hh3));
        }
        __syncthreads();
        f4 acc2 = {0.f, 0.f, 0.f, 0.f};
        #pragma unroll
        for (int k2 = 0; k2 < 4; ++k2) {
            const s8b hf = *(const s8b*)(hbw + li * 136 + k2 * 32 + lq * 8);
            acc2 = __builtin_amdgcn_mfma_f32_16x16x32_bf16(w2f[k2], hf, acc2, 0, 0, 0);
        }
        // D2[m=ch][n=pixel]: lane holds pixel = li, ch = lq*4+r
        const float um = (lsr[t * 16 + li] <= 0.5f) ? 1.f : 0.f;
        const float4 xc = *(const float4*)(xt + ((t + 1) * 18 + li + 1) * 20 + lq * 4);
        float4 nx;
        nx.x = fmaf(acc2[0] + b2v[0], um, xc.x);
        nx.y = fmaf(acc2[1] + b2v[1], um, xc.y);
        nx.z = fmaf(acc2[2] + b2v[2], um, xc.z);
        nx.w = fmaf(acc2[3] + b2v[3], um, xc.w);
        const size_t gp = ((size_t)bb * 256 + h0 + t) * 256 + (w0 + li);
        ((float4*)out)[gp * 4 + lq] = nx;
        if (lq == 0) ws_alpha[gp] = nx.w;   // lq==0,r==3 is channel 3
    }
}

// ---------------- exact fp32 alpha recompute (rare boundary pixels) ----------------
__device__ float exact_alpha(
    const float* __restrict__ x, const float* __restrict__ W1,
    const float* __restrict__ b1, const float* __restrict__ W2,
    const float* __restrict__ b2, const float* __restrict__ rand_u,
    int bb, int gh, int gw)
{
    const size_t p = ((size_t)bb * 256 + gh) * 256 + gw;
    const float xa = x[p * 16 + 3];
    if (rand_u[p] > 0.5f) return xa;   // update masked off -> alpha unchanged (exact)
    float y[48];
    #pragma unroll
    for (int k = 0; k < 48; ++k) y[k] = 0.f;
    for (int dy = 0; dy < 3; ++dy) {
        for (int dx = 0; dx < 3; ++dx) {
            const int hh = gh + dy - 1, ww = gw + dx - 1;
            if (hh < 0 || hh >= 256 || ww < 0 || ww >= 256) continue;
            const float* f = x + (((size_t)bb * 256 + hh) * 256 + ww) * 16;
            const float rw = (dy == 1) ? 2.f : 1.f;
            const float cw = (dx == 1) ? 2.f : 1.f;
            const float wx = rw * (float)(dx - 1) * 0.125f;
            const float wy = cw * (float)(dy - 1) * 0.125f;
            const bool ctr = (dy == 1 && dx == 1);
            #pragma unroll
            for (int c = 0; c < 16; ++c) {
                const float v = f[c];
                if (ctr) y[3 * c] = v;
                y[3 * c + 1] = fmaf(v, wx, y[3 * c + 1]);
                y[3 * c + 2] = fmaf(v, wy, y[3 * c + 2]);
            }
        }
    }
    float dot = b2[3];
    for (int d4 = 0; d4 < 32; ++d4) {
        const float4 a4 = *(const float4*)(b1 + d4 * 4);
        float a0 = a4.x, a1 = a4.y, a2 = a4.z, a3 = a4.w;
        for (int k = 0; k < 48; ++k) {
            const float4 w = *(const float4*)(W1 + k * 128 + d4 * 4);
            const float yk = y[k];
            a0 = fmaf(yk, w.x, a0); a1 = fmaf(yk, w.y, a1);
            a2 = fmaf(yk, w.z, a2); a3 = fmaf(yk, w.w, a3);
        }
        dot = fmaf(fmaxf(a0, 0.f), W2[(d4 * 4 + 0) * 16 + 3], dot);
        dot = fmaf(fmaxf(a1, 0.f), W2[(d4 * 4 + 1) * 16 + 3], dot);
        dot = fmaf(fmaxf(a2, 0.f), W2[(d4 * 4 + 2) * 16 + 3], dot);
        dot = fmaf(fmaxf(a3, 0.f), W2[(d4 * 4 + 3) * 16 + 3], dot);
    }
    return xa + dot;
}

// ---------------- mask kernel: 3x3 max with margin + exact fallback ----------------
__global__ __launch_bounds__(256) void ca_mask(
    const float* __restrict__ x, const float* __restrict__ W1,
    const float* __restrict__ b1, const float* __restrict__ W2,
    const float* __restrict__ b2, const float* __restrict__ rand_u,
    const float* __restrict__ alpha, const unsigned char* __restrict__ pre,
    float* __restrict__ out)
{
    __shared__ float at[18 * 20];
    const int tid = threadIdx.x;
    const int w0 = blockIdx.x * 16, h0 = blockIdx.y * 16, bb = blockIdx.z;
    for (int i = tid; i < 324; i += 256) {
        const int ly = i / 18, lx = i - ly * 18;
        const int gh = h0 + ly - 1, gw = w0 + lx - 1;
        float v = 0.f;
        if (gh >= 0 && gh < 256 && gw >= 0 && gw < 256)
            v = alpha[((size_t)bb * 256 + gh) * 256 + gw];
        at[ly * 20 + lx] = v;
    }
    __syncthreads();
    const int txx = tid & 15, tyy = tid >> 4;
    float m = at[tyy * 20 + txx];
    m = fmaxf(m, at[tyy * 20 + txx + 1]); m = fmaxf(m, at[tyy * 20 + txx + 2]);
    m = fmaxf(m, at[(tyy + 1) * 20 + txx]); m = fmaxf(m, at[(tyy + 1) * 20 + txx + 1]); m = fmaxf(m, at[(tyy + 1) * 20 + txx + 2]);
    m = fmaxf(m, at[(tyy + 2) * 20 + txx]); m = fmaxf(m, at[(tyy + 2) * 20 + txx + 1]); m = fmaxf(m, at[(tyy + 2) * 20 + txx + 2]);
    bool alive;
    if (m > 0.1f + MG) alive = true;
    else if (m <= 0.1f - MG) alive = false;
    else {
        alive = false;
        for (int nb = 0; nb < 9; ++nb) {
            if (alive) break;
            const int dy = nb / 3, dx = nb - dy * 3;
            const float a = at[(tyy + dy) * 20 + txx + dx];
            if (a > 0.1f - MG) {
                const float tr = exact_alpha(x, W1, b1, W2, b2, rand_u, bb, h0 + tyy + dy - 1, w0 + txx + dx - 1);
                if (tr > 0.1f) alive = true;
            }
        }
    }
    const size_t gp = ((size_t)bb * 256 + h0 + tyy) * 256 + (w0 + txx);
    const float sc = (alive && pre[gp]) ? 1.f : 0.f;
    float4* po = (float4*)(out + gp * 16);
    #pragma unroll
    for (int i2 = 0; i2 < 4; ++i2) {
        float4 v = po[i2]; v.x *= sc; v.y *= sc; v.z *= sc; v.w *= sc; po[i2] = v;
    }
}

extern "C" void kernel_launch(void* const* d_in, const int* in_sizes, int n_in,
                              void* d_out, int out_size, void* d_ws, size_t ws_size,
                              hipStream_t stream) {
    (void)in_sizes; (void)n_in; (void)out_size; (void)ws_size;
    const float* x  = (const float*)d_in[0];
    const float* W1 = (const float*)d_in[1];
    const float* b1 = (const float*)d_in[2];
    const float* W2 = (const float*)d_in[3];
    const float* b2 = (const float*)d_in[4];
    const float* ru = (const float*)d_in[5];
    float* out = (float*)d_out;
    float* ws_alpha = (float*)d_ws;                               // NPIX floats
    unsigned char* ws_pre = (unsigned char*)(ws_alpha + NPIX);    // NPIX bytes
    uint4* w1p = (uint4*)((char*)d_ws + (size_t)NPIX * 5);        // 1024 uint4 (16 KB), 16B-aligned
    uint4* w2p = w1p + 1024;                                      // 256 uint4 (4 KB)

    ca_prep<<<2, 256, 0, stream>>>(W1, b1, W2, w1p, w2p);
    dim3 g(16, 16, 16);
    ca_update<<<g, 256, 0, stream>>>(x, b2, ru, w1p, w2p, out, ws_alpha, ws_pre);
    ca_mask<<<g, 256, 0, stream>>>(x, W1, b1, W2, b2, ru, ws_alpha, ws_pre, out);
}

// Round 3
// 332.782 us; speedup vs baseline: 1.1756x; 1.0218x over previous
//
#include <hip/hip_runtime.h>

// Neural-CA update step, MI355X/gfx950.
// ca_prep: pack W1(+b1)/W2 into MFMA bf16 fragments in d_ws.
// ca_update: 16x16 tile, fp32 perceive -> bf16 MFMA MLP (wave-private LDS staging,
//   no inner barriers) -> out, ws_alpha, ws_pre; pushes near-threshold alpha
//   pixels (|a-0.1|<=0.04, updated only) to a worklist.
// ca_fix: one wave per worklist entry recomputes exact fp32 alpha (lane-parallel
//   over hid units, shuffle reduce) and overwrites ws_alpha -> mask decisions
//   are exact despite bf16 GEMMs.
// ca_mask: branchless 3x3 max; life mask is {0,1} so it only ZEROES dead pixels
//   (~0.4%) -- no read-modify-write of the 64MB output.

#define NC 16
#define NHID 128
#define NPIX (16 * 256 * 256)
#define MG 0.04f
#define MAXFIX 65536

typedef __attribute__((ext_vector_type(8))) short s8b;   // 8 x bf16 (4 VGPRs)
typedef __attribute__((ext_vector_type(4))) float f4;

__device__ __forceinline__ unsigned short f2bf(float f) {
    union { float f; unsigned int u; } v; v.f = f;
    unsigned int r = (v.u + 0x7FFFu + ((v.u >> 16) & 1u)) >> 16;  // RNE
    return (unsigned short)r;
}
__device__ __forceinline__ unsigned int pack2(float a, float b) {
    return (unsigned int)f2bf(a) | ((unsigned int)f2bf(b) << 16);
}

// ---------------- prep: pack weights into MFMA fragment order ----------------
__global__ __launch_bounds__(256) void ca_prep(
    const float* __restrict__ W1, const float* __restrict__ b1,
    const float* __restrict__ W2, uint4* __restrict__ w1p, uint4* __restrict__ w2p)
{
    const int tid = threadIdx.x;
    if (blockIdx.x == 0) {
        for (int idx = tid; idx < 1024; idx += 256) {
            const int fid = idx >> 6, lane = idx & 63;
            const int k0 = fid >> 3, mt = fid & 7;
            const int q = lane >> 4, i = lane & 15;
            unsigned int u[4];
            #pragma unroll
            for (int jp = 0; jp < 4; ++jp) {
                int k = k0 * 32 + q * 8 + jp * 2;
                float v0 = (k < 48) ? W1[k * 128 + mt * 16 + i] : ((k == 48) ? b1[mt * 16 + i] : 0.f);
                k++;
                float v1 = (k < 48) ? W1[k * 128 + mt * 16 + i] : ((k == 48) ? b1[mt * 16 + i] : 0.f);
                u[jp] = pack2(v0, v1);
            }
            w1p[idx] = make_uint4(u[0], u[1], u[2], u[3]);
        }
    } else {
        for (int idx = tid; idx < 256; idx += 256) {
            const int k2 = idx >> 6, lane = idx & 63;
            const int q = lane >> 4, i = lane & 15;
            unsigned int u[4];
            #pragma unroll
            for (int jp = 0; jp < 4; ++jp) {
                const int k = k2 * 32 + q * 8 + jp * 2;
                u[jp] = pack2(W2[k * 16 + i], W2[(k + 1) * 16 + i]);
            }
            w2p[idx] = make_uint4(u[0], u[1], u[2], u[3]);
        }
    }
}

// ---------------- main update kernel ----------------
__global__ __launch_bounds__(256, 2) void ca_update(
    const float* __restrict__ x, const float* __restrict__ b2,
    const float* __restrict__ rand_u, const uint4* __restrict__ w1p,
    const uint4* __restrict__ w2p, float* __restrict__ out,
    float* __restrict__ ws_alpha, unsigned char* __restrict__ ws_pre,
    unsigned int* __restrict__ fix_cnt, unsigned int* __restrict__ fix_list)
{
    __shared__ __align__(16) float xt[18 * 18 * 20];
    __shared__ __align__(16) unsigned short yfs[4 * 2 * 528];  // per-wave y B-frags
    __shared__ __align__(16) unsigned short hbs[4 * 16 * 136]; // per-wave h rows
    __shared__ float lsr[256];

    const int tid  = threadIdx.x;
    const int lane = tid & 63;
    const int li   = lane & 15;
    const int lq   = lane >> 4;
    const int wv   = tid >> 6;
    const int tx   = tid & 15, ty = tid >> 4;
    const int w0 = blockIdx.x * 16, h0 = blockIdx.y * 16, bb = blockIdx.z;

    s8b w1f[2][8], w2f[4];
    const s8b* w1s = (const s8b*)w1p;
    const s8b* w2s = (const s8b*)w2p;
    #pragma unroll
    for (int k0 = 0; k0 < 2; ++k0)
        #pragma unroll
        for (int mt = 0; mt < 8; ++mt)
            w1f[k0][mt] = w1s[(k0 * 8 + mt) * 64 + lane];
    #pragma unroll
    for (int k2 = 0; k2 < 4; ++k2) w2f[k2] = w2s[k2 * 64 + lane];
    float b2v[4];
    #pragma unroll
    for (int r = 0; r < 4; ++r) b2v[r] = b2[lq * 4 + r];

    for (int i = tid; i < 324; i += 256) {
        const int ly = i / 18, lx = i - ly * 18;
        const int gh = h0 + ly - 1, gw = w0 + lx - 1;
        float4 v0, v1, v2, v3;
        if (gh >= 0 && gh < 256 && gw >= 0 && gw < 256) {
            const float4* p = (const float4*)(x + (((size_t)bb * 256 + gh) * 256 + gw) * NC);
            v0 = p[0]; v1 = p[1]; v2 = p[2]; v3 = p[3];
        } else {
            v0 = v1 = v2 = v3 = make_float4(0.f, 0.f, 0.f, 0.f);
        }
        float4* t = (float4*)(xt + i * 20);
        t[0] = v0; t[1] = v1; t[2] = v2; t[3] = v3;
    }
    const size_t gpix = ((size_t)bb * 256 + h0 + ty) * 256 + (w0 + tx);
    lsr[tid] = rand_u[gpix];
    __syncthreads();

    const int o_mm = ((ty + 0) * 18 + tx + 0) * 20, o_m0 = ((ty + 0) * 18 + tx + 1) * 20, o_mp = ((ty + 0) * 18 + tx + 2) * 20;
    const int o_0m = ((ty + 1) * 18 + tx + 0) * 20, o_cc = ((ty + 1) * 18 + tx + 1) * 20, o_0p = ((ty + 1) * 18 + tx + 2) * 20;
    const int o_pm = ((ty + 2) * 18 + tx + 0) * 20, o_p0 = ((ty + 2) * 18 + tx + 1) * 20, o_pp = ((ty + 2) * 18 + tx + 2) * 20;

    float am = xt[o_mm + 3];
    am = fmaxf(am, xt[o_m0 + 3]); am = fmaxf(am, xt[o_mp + 3]);
    am = fmaxf(am, xt[o_0m + 3]); am = fmaxf(am, xt[o_cc + 3]); am = fmaxf(am, xt[o_0p + 3]);
    am = fmaxf(am, xt[o_pm + 3]); am = fmaxf(am, xt[o_p0 + 3]); am = fmaxf(am, xt[o_pp + 3]);
    ws_pre[gpix] = (am > 0.1f) ? (unsigned char)1 : (unsigned char)0;

    unsigned int yu[24];
    #pragma unroll
    for (int cq = 0; cq < 4; ++cq) {
        const int co = cq * 4;
        float4 vmm = *(const float4*)(xt + o_mm + co); const float* pmm = (const float*)&vmm;
        float4 vm0 = *(const float4*)(xt + o_m0 + co); const float* pm0 = (const float*)&vm0;
        float4 vmp = *(const float4*)(xt + o_mp + co); const float* pmp = (const float*)&vmp;
        float4 v0m = *(const float4*)(xt + o_0m + co); const float* p0m = (const float*)&v0m;
        float4 vcc = *(const float4*)(xt + o_cc + co); const float* pcc = (const float*)&vcc;
        float4 v0p = *(const float4*)(xt + o_0p + co); const float* p0p = (const float*)&v0p;
        float4 vpm = *(const float4*)(xt + o_pm + co); const float* ppm = (const float*)&vpm;
        float4 vp0 = *(const float4*)(xt + o_p0 + co); const float* pp0 = (const float*)&vp0;
        float4 vpp = *(const float4*)(xt + o_pp + co); const float* ppp = (const float*)&vpp;
        float yl[12];
        #pragma unroll
        for (int cc = 0; cc < 4; ++cc) {
            const float xmm = pmm[cc], xm0 = pm0[cc], xmp = pmp[cc];
            const float x0m = p0m[cc], xcc = pcc[cc], x0p = p0p[cc];
            const float xpm = ppm[cc], xp0 = pp0[cc], xpp = ppp[cc];
            yl[cc * 3 + 0] = xcc;
            yl[cc * 3 + 1] = ((xmp - xmm) + 2.f * (x0p - x0m) + (xpp - xpm)) * 0.125f;
            yl[cc * 3 + 2] = ((xpm - xmm) + 2.f * (xp0 - xm0) + (xpp - xmp)) * 0.125f;
        }
        #pragma unroll
        for (int m2 = 0; m2 < 6; ++m2) yu[cq * 6 + m2] = pack2(yl[2 * m2], yl[2 * m2 + 1]);
    }

    unsigned short* yfw = yfs + wv * (2 * 528);
    unsigned short* hbw = hbs + wv * (16 * 136);

    // wave-private dataflow: no block barriers needed inside this loop
    for (int s = 0; s < 4; ++s) {
        const int t = wv * 4 + s;
        if ((ty & 3) == s) {
            #pragma unroll
            for (int q = 0; q < 4; ++q)
                *(uint4*)(yfw + (q * 16 + tx) * 8) = make_uint4(yu[q * 4], yu[q * 4 + 1], yu[q * 4 + 2], yu[q * 4 + 3]);
            *(uint4*)(yfw + 528 + (0 * 16 + tx) * 8) = make_uint4(yu[16], yu[17], yu[18], yu[19]);
            *(uint4*)(yfw + 528 + (1 * 16 + tx) * 8) = make_uint4(yu[20], yu[21], yu[22], yu[23]);
            *(uint4*)(yfw + 528 + (2 * 16 + tx) * 8) = make_uint4(0x3F80u, 0u, 0u, 0u);  // bias row k=48 -> 1.0
            *(uint4*)(yfw + 528 + (3 * 16 + tx) * 8) = make_uint4(0u, 0u, 0u, 0u);
        }
        const s8b ya0 = *(const s8b*)(yfw + lane * 8);
        const s8b ya1 = *(const s8b*)(yfw + 528 + lane * 8);
        f4 acc1[8];
        #pragma unroll
        for (int mt = 0; mt < 8; ++mt) { f4 z = {0.f, 0.f, 0.f, 0.f}; acc1[mt] = z; }
        #pragma unroll
        for (int mt = 0; mt < 8; ++mt)
            acc1[mt] = __builtin_amdgcn_mfma_f32_16x16x32_bf16(w1f[0][mt], ya0, acc1[mt], 0, 0, 0);
        #pragma unroll
        for (int mt = 0; mt < 8; ++mt)
            acc1[mt] = __builtin_amdgcn_mfma_f32_16x16x32_bf16(w1f[1][mt], ya1, acc1[mt], 0, 0, 0);
        #pragma unroll
        for (int mt = 0; mt < 8; ++mt) {
            const float hh0 = fmaxf(acc1[mt][0], 0.f), hh1 = fmaxf(acc1[mt][1], 0.f);
            const float hh2 = fmaxf(acc1[mt][2], 0.f), hh3 = fmaxf(acc1[mt][3], 0.f);
            *(uint2*)(hbw + li * 136 + mt * 16 + lq * 4) = make_uint2(pack2(hh0, hh1), pack2(hh2, hh3));
        }
        f4 acc2 = {0.f, 0.f, 0.f, 0.f};
        #pragma unroll
        for (int k2 = 0; k2 < 4; ++k2) {
            const s8b hf = *(const s8b*)(hbw + li * 136 + k2 * 32 + lq * 8);
            acc2 = __builtin_amdgcn_mfma_f32_16x16x32_bf16(w2f[k2], hf, acc2, 0, 0, 0);
        }
        const float um = (lsr[t * 16 + li] <= 0.5f) ? 1.f : 0.f;
        const float4 xc = *(const float4*)(xt + ((t + 1) * 18 + li + 1) * 20 + lq * 4);
        float4 nx;
        nx.x = fmaf(acc2[0] + b2v[0], um, xc.x);
        nx.y = fmaf(acc2[1] + b2v[1], um, xc.y);
        nx.z = fmaf(acc2[2] + b2v[2], um, xc.z);
        nx.w = fmaf(acc2[3] + b2v[3], um, xc.w);
        const size_t gp = ((size_t)bb * 256 + h0 + t) * 256 + (w0 + li);
        ((float4*)out)[gp * 4 + lq] = nx;
        if (lq == 0) {
            ws_alpha[gp] = nx.w;
            // near-threshold updated pixels -> exact-recompute worklist
            if (um != 0.f && fabsf(nx.w - 0.1f) <= MG) {
                unsigned int idx = atomicAdd(fix_cnt, 1u);
                if (idx < MAXFIX) fix_list[idx] = (unsigned int)gp;
            }
        }
    }
}

// ---------------- fixup: exact fp32 alpha for worklist pixels ----------------
__global__ __launch_bounds__(64) void ca_fix(
    const float* __restrict__ x, const float* __restrict__ W1,
    const float* __restrict__ b1, const float* __restrict__ W2,
    const float* __restrict__ b2,
    const unsigned int* __restrict__ fix_cnt, const unsigned int* __restrict__ fix_list,
    float* __restrict__ ws_alpha)
{
    __shared__ float ysh[48];
    const int lane = threadIdx.x;
    unsigned int n = *fix_cnt;
    if (n > MAXFIX) n = MAXFIX;
    for (unsigned int e = blockIdx.x; e < n; e += gridDim.x) {
        const unsigned int pix = fix_list[e];
        const int bb = pix >> 16, h = (pix >> 8) & 255, w = pix & 255;
        if (lane < 48) {
            const int c = lane / 3, j = lane - c * 3;
            float v = 0.f;
            #pragma unroll
            for (int dy = 0; dy < 3; ++dy) {
                #pragma unroll
                for (int dxx = 0; dxx < 3; ++dxx) {
                    const int hh = h + dy - 1, ww = w + dxx - 1;
                    if (hh < 0 || hh >= 256 || ww < 0 || ww >= 256) continue;
                    const float f = x[(((size_t)bb * 256 + hh) * 256 + ww) * 16 + c];
                    float wgt;
                    if (j == 0) wgt = (dy == 1 && dxx == 1) ? 1.f : 0.f;
                    else if (j == 1) wgt = ((dy == 1) ? 2.f : 1.f) * (float)(dxx - 1) * 0.125f;
                    else wgt = ((dxx == 1) ? 2.f : 1.f) * (float)(dy - 1) * 0.125f;
                    v = fmaf(f, wgt, v);
                }
            }
            ysh[lane] = v;
        }
        __syncthreads();
        float dot = 0.f;
        #pragma unroll
        for (int t = 0; t < 2; ++t) {
            const int d = t * 64 + lane;
            float a = b1[d];
            #pragma unroll
            for (int k = 0; k < 48; ++k)
                a = fmaf(ysh[k], W1[k * 128 + d], a);
            dot = fmaf(fmaxf(a, 0.f), W2[d * 16 + 3], dot);
        }
        #pragma unroll
        for (int off = 32; off > 0; off >>= 1)
            dot += __shfl_down(dot, off, 64);
        if (lane == 0)
            ws_alpha[pix] = x[(size_t)pix * 16 + 3] + dot + b2[3];
        __syncthreads();
    }
}

// ---------------- mask: 3x3 max, zero dead pixels only ----------------
__global__ __launch_bounds__(256) void ca_mask(
    const float* __restrict__ alpha, const unsigned char* __restrict__ pre,
    float* __restrict__ out)
{
    __shared__ float at[18 * 20];
    const int tid = threadIdx.x;
    const int w0 = blockIdx.x * 16, h0 = blockIdx.y * 16, bb = blockIdx.z;
    for (int i = tid; i < 324; i += 256) {
        const int ly = i / 18, lx = i - ly * 18;
        const int gh = h0 + ly - 1, gw = w0 + lx - 1;
        float v = 0.f;
        if (gh >= 0 && gh < 256 && gw >= 0 && gw < 256)
            v = alpha[((size_t)bb * 256 + gh) * 256 + gw];
        at[ly * 20 + lx] = v;
    }
    __syncthreads();
    const int txx = tid & 15, tyy = tid >> 4;
    float m = at[tyy * 20 + txx];
    m = fmaxf(m, at[tyy * 20 + txx + 1]); m = fmaxf(m, at[tyy * 20 + txx + 2]);
    m = fmaxf(m, at[(tyy + 1) * 20 + txx]); m = fmaxf(m, at[(tyy + 1) * 20 + txx + 1]); m = fmaxf(m, at[(tyy + 1) * 20 + txx + 2]);
    m = fmaxf(m, at[(tyy + 2) * 20 + txx]); m = fmaxf(m, at[(tyy + 2) * 20 + txx + 1]); m = fmaxf(m, at[(tyy + 2) * 20 + txx + 2]);
    const size_t gp = ((size_t)bb * 256 + h0 + tyy) * 256 + (w0 + txx);
    const bool alive = (m > 0.1f) && pre[gp];
    if (!alive) {
        float4* po = (float4*)(out + gp * 16);
        const float4 z = make_float4(0.f, 0.f, 0.f, 0.f);
        po[0] = z; po[1] = z; po[2] = z; po[3] = z;
    }
}

extern "C" void kernel_launch(void* const* d_in, const int* in_sizes, int n_in,
                              void* d_out, int out_size, void* d_ws, size_t ws_size,
                              hipStream_t stream) {
    (void)in_sizes; (void)n_in; (void)out_size; (void)ws_size;
    const float* x  = (const float*)d_in[0];
    const float* W1 = (const float*)d_in[1];
    const float* b1 = (const float*)d_in[2];
    const float* W2 = (const float*)d_in[3];
    const float* b2 = (const float*)d_in[4];
    const float* ru = (const float*)d_in[5];
    float* out = (float*)d_out;

    char* ws = (char*)d_ws;
    float* ws_alpha       = (float*)ws;                                // 4 MiB
    unsigned char* ws_pre = (unsigned char*)(ws + (size_t)NPIX * 4);   // 1 MiB
    uint4* w1p            = (uint4*)(ws + (size_t)NPIX * 5);           // 16 KiB
    uint4* w2p            = w1p + 1024;                                // 4 KiB
    unsigned int* fix_cnt = (unsigned int*)(ws + (size_t)NPIX * 5 + 20480);
    unsigned int* fix_list= fix_cnt + 4;                               // 256 KiB

    hipMemsetAsync(fix_cnt, 0, sizeof(unsigned int), stream);
    ca_prep<<<2, 256, 0, stream>>>(W1, b1, W2, w1p, w2p);
    dim3 g(16, 16, 16);
    ca_update<<<g, 256, 0, stream>>>(x, b2, ru, w1p, w2p, out, ws_alpha, ws_pre, fix_cnt, fix_list);
    ca_fix<<<4096, 64, 0, stream>>>(x, W1, b1, W2, b2, fix_cnt, fix_list, ws_alpha);
    ca_mask<<<g, 256, 0, stream>>>(ws_alpha, ws_pre, out);
}